// Round 2
// baseline (348.973 us; speedup 1.0000x reference)
//
#include <hip/hip_runtime.h>
#include <cfloat>
#include <climits>

#define NTRAIN 50000
#define DIM 64
#define BQ 128
#define NCLS 10
#define KSEL 16

#define SAMPLE 1024          // sample rows for threshold
#define CAPMAX 1536          // candidate cap per query (expect ~780 +- 28)
#define MARGIN 1e-3f

#define TPAD 68              // 17 float4 per row: bank-group = 4*(row&7) -> conflict-free
#define BTHREADS 256         // 4 waves: 2 q-groups x 2 r-groups
#define TILE_R 128
#define TILE_Q 64
#define NSLICE ((NTRAIN + TILE_R - 1) / TILE_R)   // 391, last tile 80 rows

// Shared by K1 and K3 -> bit-identical distances (threshold guarantee is exact).
// Wave tile 32q x 64r; per lane 4q x 8r. lane: qg=lane>>3, rg=lane&7;
// queries qg+8i, rows rg+8j -> each ds_read_b128 instr: 8 distinct addrs
// (8-lane broadcast), banks 4*(rg or qg) -> 8 disjoint bank-groups, 0 conflict.
__device__ __forceinline__ void tile_distance(
    const float* __restrict__ qs, const float* __restrict__ ts,
    int waveQ, int waveR, int qg, int rg, float acc[4][8])
{
#pragma unroll
    for (int i = 0; i < 4; ++i)
#pragma unroll
        for (int j = 0; j < 8; ++j) acc[i][j] = 0.0f;

#pragma unroll 4
    for (int c = 0; c < 16; ++c) {
        float4 qv[4], tv[8];
#pragma unroll
        for (int i = 0; i < 4; ++i)
            qv[i] = *(const float4*)&qs[(waveQ + qg + 8 * i) * TPAD + 4 * c];
#pragma unroll
        for (int j = 0; j < 8; ++j)
            tv[j] = *(const float4*)&ts[(waveR + rg + 8 * j) * TPAD + 4 * c];
#pragma unroll
        for (int i = 0; i < 4; ++i)
#pragma unroll
            for (int j = 0; j < 8; ++j) {
                const float s01 = fabsf(tv[j].x - qv[i].x) + fabsf(tv[j].y - qv[i].y);
                const float s23 = fabsf(tv[j].z - qv[i].z) + fabsf(tv[j].w - qv[i].w);
                acc[i][j] += s01 + s23;
            }
    }
}

__device__ __forceinline__ void stage_tiles(
    float* qs, float* ts, const float* __restrict__ xtest,
    const float* __restrict__ train, int q0, int r0, int nr, int tid)
{
    for (int f = tid; f < TILE_Q * (DIM / 4); f += BTHREADS) {
        const int q = f >> 4, c = f & 15;
        *(float4*)&qs[q * TPAD + 4 * c] =
            *(const float4*)&xtest[(size_t)(q0 + q) * DIM + 4 * c];
    }
    for (int f = tid; f < nr * (DIM / 4); f += BTHREADS) {
        const int r = f >> 4, c = f & 15;
        *(float4*)&ts[r * TPAD + 4 * c] =
            *(const float4*)&train[(size_t)(r0 + r) * DIM + 4 * c];
    }
    __syncthreads();
}

// K1: exact distances for sample rows -> samp[q][r], r in [0, SAMPLE)
__global__ __launch_bounds__(BTHREADS) void knn_sample(
    const float* __restrict__ train, const float* __restrict__ xtest,
    float* __restrict__ samp)
{
    __shared__ float qs[TILE_Q * TPAD];
    __shared__ float ts[TILE_R * TPAD];
    const int tid = threadIdx.x, w = tid >> 6, lane = tid & 63;
    const int qg = lane >> 3, rg = lane & 7;
    const int waveQ = (w >> 1) * 32, waveR = (w & 1) * 64;
    const int q0 = blockIdx.y * TILE_Q, r0 = blockIdx.x * TILE_R;

    stage_tiles(qs, ts, xtest, train, q0, r0, TILE_R, tid);

    float acc[4][8];
    tile_distance(qs, ts, waveQ, waveR, qg, rg, acc);

#pragma unroll
    for (int i = 0; i < 4; ++i) {
        const int q = q0 + waveQ + qg + 8 * i;
#pragma unroll
        for (int j = 0; j < 8; ++j) {
            const int r = r0 + waveR + rg + 8 * j;
            samp[(size_t)q * SAMPLE + r] = acc[i][j];
        }
    }
}

// K2: tau[q] = 16th smallest sample distance + margin; zero counters
__global__ __launch_bounds__(64) void knn_tau(
    const float* __restrict__ samp, float* __restrict__ tau, int* __restrict__ cnt)
{
    const int b = blockIdx.x, lane = threadIdx.x;
    float ld[KSEL]; int li[KSEL];
#pragma unroll
    for (int j = 0; j < KSEL; ++j) { ld[j] = FLT_MAX; li[j] = INT_MAX; }

#pragma unroll
    for (int k = 0; k < SAMPLE / 64; ++k) {
        const int   iv = lane + 64 * k;
        const float dv = samp[(size_t)b * SAMPLE + iv];
        if (dv < ld[KSEL - 1] || (dv == ld[KSEL - 1] && iv < li[KSEL - 1])) {
            ld[KSEL - 1] = dv; li[KSEL - 1] = iv;
#pragma unroll
            for (int j = KSEL - 1; j > 0; --j)
                if (ld[j] < ld[j - 1] || (ld[j] == ld[j - 1] && li[j] < li[j - 1])) {
                    float td = ld[j]; ld[j] = ld[j - 1]; ld[j - 1] = td;
                    int   ti = li[j]; li[j] = li[j - 1]; li[j - 1] = ti;
                }
        }
    }

    float hd = ld[0]; int hi = li[0]; int c = 0; float last = 0.0f;
    for (int r = 0; r < KSEL; ++r) {
        float wd = hd; int wi = hi;
#pragma unroll
        for (int sh = 1; sh < 64; sh <<= 1) {
            const float xd = __shfl_xor(wd, sh);
            const int   xi = __shfl_xor(wi, sh);
            if (xd < wd || (xd == wd && xi < wi)) { wd = xd; wi = xi; }
        }
        if (wi == hi) {
            ++c;
            float nd = FLT_MAX; int ni = INT_MAX;
#pragma unroll
            for (int q = 1; q < KSEL; ++q)
                if (c == q) { nd = ld[q]; ni = li[q]; }
            hd = nd; hi = ni;
        }
        last = wd;
    }
    if (lane == 0) { tau[b] = last + MARGIN; cnt[b] = 0; }
}

// K3: full distance scan, append rows with d <= tau[q] to candidate list
__global__ __launch_bounds__(BTHREADS, 3) void knn_scan(
    const float* __restrict__ train, const float* __restrict__ xtest,
    const float* __restrict__ tau, int* __restrict__ cnt,
    float* __restrict__ cand_d, int* __restrict__ cand_i, int cap)
{
    __shared__ float qs[TILE_Q * TPAD];
    __shared__ float ts[TILE_R * TPAD];
    const int tid = threadIdx.x, w = tid >> 6, lane = tid & 63;
    const int qg = lane >> 3, rg = lane & 7;
    const int waveQ = (w >> 1) * 32, waveR = (w & 1) * 64;
    const int q0 = blockIdx.y * TILE_Q, r0 = blockIdx.x * TILE_R;
    const int nr = min(TILE_R, NTRAIN - r0);

    stage_tiles(qs, ts, xtest, train, q0, r0, nr, tid);

    float acc[4][8];
    tile_distance(qs, ts, waveQ, waveR, qg, rg, acc);

    float tv[4];
#pragma unroll
    for (int i = 0; i < 4; ++i) tv[i] = tau[q0 + waveQ + qg + 8 * i];

#pragma unroll
    for (int i = 0; i < 4; ++i) {
        const int q = q0 + waveQ + qg + 8 * i;
#pragma unroll
        for (int j = 0; j < 8; ++j) {
            const int r = r0 + waveR + rg + 8 * j;
            if (r < NTRAIN && acc[i][j] <= tv[i]) {
                const int pos = atomicAdd(&cnt[q], 1);
                if (pos < cap) {
                    cand_d[(size_t)q * cap + pos] = acc[i][j];
                    cand_i[(size_t)q * cap + pos] = r;
                }
            }
        }
    }
}

// K4: exact lex-(d,idx) top-16 over candidates, vote, argmax
__global__ __launch_bounds__(64) void knn_final(
    const float* __restrict__ cand_d, const int* __restrict__ cand_i,
    const int* __restrict__ cnt, const float* __restrict__ ttarget,
    int* __restrict__ out, int cap)
{
    const int b = blockIdx.x, lane = threadIdx.x;
    const int m = min(cnt[b], cap);

    float ld[KSEL]; int li[KSEL];
#pragma unroll
    for (int j = 0; j < KSEL; ++j) { ld[j] = FLT_MAX; li[j] = INT_MAX; }

    for (int q = lane; q < m; q += 64) {
        const float dv = cand_d[(size_t)b * cap + q];
        const int   iv = cand_i[(size_t)b * cap + q];
        if (dv < ld[KSEL - 1] || (dv == ld[KSEL - 1] && iv < li[KSEL - 1])) {
            ld[KSEL - 1] = dv; li[KSEL - 1] = iv;
#pragma unroll
            for (int j = KSEL - 1; j > 0; --j)
                if (ld[j] < ld[j - 1] || (ld[j] == ld[j - 1] && li[j] < li[j - 1])) {
                    float td = ld[j]; ld[j] = ld[j - 1]; ld[j - 1] = td;
                    int   ti = li[j]; li[j] = li[j - 1]; li[j - 1] = ti;
                }
        }
    }

    float hd = ld[0]; int hi = li[0]; int c = 0;
    float v = 0.0f;
    for (int r = 0; r < KSEL; ++r) {
        float wd = hd; int wi = hi;
#pragma unroll
        for (int sh = 1; sh < 64; sh <<= 1) {
            const float xd = __shfl_xor(wd, sh);
            const int   xi = __shfl_xor(wi, sh);
            if (xd < wd || (xd == wd && xi < wi)) { wd = xd; wi = xi; }
        }
        if (wi == hi) {
            ++c;
            float nd = FLT_MAX; int ni = INT_MAX;
#pragma unroll
            for (int q = 1; q < KSEL; ++q)
                if (c == q) { nd = ld[q]; ni = li[q]; }
            hd = nd; hi = ni;
        }
        if (lane < NCLS && wi >= 0 && wi < NTRAIN)
            v += ttarget[(size_t)wi * NCLS + lane];
    }

    float bv = (lane < NCLS) ? v : -1.0f;
    int   bc = lane;
#pragma unroll
    for (int sh = 1; sh < 64; sh <<= 1) {
        const float xv = __shfl_xor(bv, sh);
        const int   xc = __shfl_xor(bc, sh);
        if (xv > bv || (xv == bv && xc < bc)) { bv = xv; bc = xc; }
    }
    if (lane == 0) out[b] = bc;
}

extern "C" void kernel_launch(void* const* d_in, const int* in_sizes, int n_in,
                              void* d_out, int out_size, void* d_ws, size_t ws_size,
                              hipStream_t stream) {
    const float* train   = (const float*)d_in[0];
    const float* ttarget = (const float*)d_in[1];
    const float* xtest   = (const float*)d_in[2];
    int* out = (int*)d_out;

    char* ws = (char*)d_ws;
    float* samp = (float*)ws;                               // 128*1024*4 = 512 KB
    float* tau  = (float*)(ws + 524288);                    // 512 B
    int*   cnt  = (int*)(ws + 524800);                      // 512 B
    char*  cand = ws + 525312;

    size_t rem = (ws_size > 525312) ? ws_size - 525312 : 0;
    size_t cap_s = rem / ((size_t)BQ * 8);
    int cap = (cap_s > (size_t)CAPMAX) ? CAPMAX : (int)cap_s;
    if (cap < 64) cap = 64;                                 // degenerate safeguard

    float* cand_d = (float*)cand;
    int*   cand_i = (int*)(cand + (size_t)BQ * cap * sizeof(float));

    hipLaunchKernelGGL(knn_sample, dim3(SAMPLE / TILE_R, 2), dim3(BTHREADS), 0, stream,
                       train, xtest, samp);
    hipLaunchKernelGGL(knn_tau, dim3(BQ), dim3(64), 0, stream, samp, tau, cnt);
    hipLaunchKernelGGL(knn_scan, dim3(NSLICE, 2), dim3(BTHREADS), 0, stream,
                       train, xtest, tau, cnt, cand_d, cand_i, cap);
    hipLaunchKernelGGL(knn_final, dim3(BQ), dim3(64), 0, stream,
                       cand_d, cand_i, cnt, ttarget, out, cap);
}

// Round 3
// 283.371 us; speedup vs baseline: 1.2315x; 1.2315x over previous
//
#include <hip/hip_runtime.h>
#include <cfloat>
#include <climits>

#define NTRAIN 50000
#define DIM 64
#define BQ 128
#define NCLS 10
#define KSEL 16
#define TB 16                 // test points per block (2 per wave)
#define GROUPS (BQ / TB)      // 8
#define THREADS 512
#define TROWS 128             // rows per LDS tile; lane owns rows {lane, lane+64}
#define TPAD 68               // bank-group 4*(row+c)%32 -> 8-lane phases conflict-free (R1: 0 conflicts)

__global__ __launch_bounds__(THREADS) void knn_partial(
    const float* __restrict__ train, const float* __restrict__ xtest,
    float* __restrict__ cand_d, int* __restrict__ cand_i,
    int nslices, int slice_len)
{
    __shared__ float tile[TROWS * TPAD];    // 34.8 KB

    const int bx   = blockIdx.x;
    const int s    = bx % nslices;          // slice id
    const int g    = bx / nslices;          // query group
    const int tid  = threadIdx.x;
    const int w    = tid >> 6;
    const int lane = tid & 63;

    const int row0 = s * slice_len;
    const int row1 = min(NTRAIN, row0 + slice_len);

    // queries in registers (one-time broadcast load; all lanes same address)
    float4 qa[DIM / 4], qb[DIM / 4];
    {
        const float* q0p = &xtest[(size_t)(g * TB + 2 * w) * DIM];
        const float* q1p = q0p + DIM;
#pragma unroll
        for (int c = 0; c < DIM / 4; ++c) {
            qa[c] = *(const float4*)&q0p[4 * c];
            qb[c] = *(const float4*)&q1p[4 * c];
        }
    }

    // per-lane top-16 (sorted ascending), static indexing only
    float d0[KSEL], d1[KSEL];
    int   i0[KSEL], i1[KSEL];
#pragma unroll
    for (int j = 0; j < KSEL; ++j) { d0[j] = FLT_MAX; d1[j] = FLT_MAX; i0[j] = INT_MAX; i1[j] = INT_MAX; }

    // staging: thread covers float4 (r = tid>>4 + 32k, c = tid&15), k=0..3
    const int pr = tid >> 4, pc = tid & 15;
    float4 pf[4];
    {
        const int nr = min(TROWS, row1 - row0);
#pragma unroll
        for (int k = 0; k < 4; ++k) {
            const int r = pr + 32 * k;
            if (r < nr) pf[k] = *(const float4*)&train[(size_t)(row0 + r) * DIM + 4 * pc];
        }
    }

    for (int base = row0; base < row1; base += TROWS) {
        const int nr = min(TROWS, row1 - base);
        __syncthreads();                    // previous tile's readers done
#pragma unroll
        for (int k = 0; k < 4; ++k) {
            const int r = pr + 32 * k;
            if (r < nr) *(float4*)&tile[r * TPAD + 4 * pc] = pf[k];
        }
        __syncthreads();                    // tile ready

        // issue next tile's global loads now; they drain at the NEXT barrier,
        // after ~3.5K cycles of compute has hidden the latency
        const int nbase = base + TROWS;
        if (nbase < row1) {
            const int nnr = min(TROWS, row1 - nbase);
#pragma unroll
            for (int k = 0; k < 4; ++k) {
                const int r = pr + 32 * k;
                if (r < nnr) pf[k] = *(const float4*)&train[(size_t)(nbase + r) * DIM + 4 * pc];
            }
        }

        // distances: rows lane, lane+64 x queries a, b
        // summation structure bit-identical to R1 (left-assoc f32 chain, f64 accumulate)
        double a0a = 0.0, a0b = 0.0, a1a = 0.0, a1b = 0.0;
        const float* tr0 = &tile[lane * TPAD];
        const float* tr1 = &tile[(lane + 64) * TPAD];
#pragma unroll
        for (int c = 0; c < DIM / 4; ++c) {
            const float4 t0 = *(const float4*)&tr0[4 * c];
            const float4 t1 = *(const float4*)&tr1[4 * c];
            const float s0a = fabsf(t0.x - qa[c].x) + fabsf(t0.y - qa[c].y) +
                              fabsf(t0.z - qa[c].z) + fabsf(t0.w - qa[c].w);
            const float s0b = fabsf(t0.x - qb[c].x) + fabsf(t0.y - qb[c].y) +
                              fabsf(t0.z - qb[c].z) + fabsf(t0.w - qb[c].w);
            const float s1a = fabsf(t1.x - qa[c].x) + fabsf(t1.y - qa[c].y) +
                              fabsf(t1.z - qa[c].z) + fabsf(t1.w - qa[c].w);
            const float s1b = fabsf(t1.x - qb[c].x) + fabsf(t1.y - qb[c].y) +
                              fabsf(t1.z - qb[c].z) + fabsf(t1.w - qb[c].w);
            a0a += (double)s0a; a0b += (double)s0b;
            a1a += (double)s1a; a1b += (double)s1b;
        }

        // inserts in increasing row order: base+lane, then base+64+lane (matches R1 order)
        {
            const float f = (float)a0a; const int gi = base + lane;
            if (lane < nr && f < d0[KSEL - 1]) {
                d0[KSEL - 1] = f; i0[KSEL - 1] = gi;
#pragma unroll
                for (int j = KSEL - 1; j > 0; --j)
                    if (d0[j] < d0[j - 1]) {
                        float td = d0[j]; d0[j] = d0[j - 1]; d0[j - 1] = td;
                        int   ti = i0[j]; i0[j] = i0[j - 1]; i0[j - 1] = ti;
                    }
            }
        }
        {
            const float f = (float)a0b; const int gi = base + lane;
            if (lane < nr && f < d1[KSEL - 1]) {
                d1[KSEL - 1] = f; i1[KSEL - 1] = gi;
#pragma unroll
                for (int j = KSEL - 1; j > 0; --j)
                    if (d1[j] < d1[j - 1]) {
                        float td = d1[j]; d1[j] = d1[j - 1]; d1[j - 1] = td;
                        int   ti = i1[j]; i1[j] = i1[j - 1]; i1[j - 1] = ti;
                    }
            }
        }
        {
            const float f = (float)a1a; const int gi = base + 64 + lane;
            if (lane + 64 < nr && f < d0[KSEL - 1]) {
                d0[KSEL - 1] = f; i0[KSEL - 1] = gi;
#pragma unroll
                for (int j = KSEL - 1; j > 0; --j)
                    if (d0[j] < d0[j - 1]) {
                        float td = d0[j]; d0[j] = d0[j - 1]; d0[j - 1] = td;
                        int   ti = i0[j]; i0[j] = i0[j - 1]; i0[j - 1] = ti;
                    }
            }
        }
        {
            const float f = (float)a1b; const int gi = base + 64 + lane;
            if (lane + 64 < nr && f < d1[KSEL - 1]) {
                d1[KSEL - 1] = f; i1[KSEL - 1] = gi;
#pragma unroll
                for (int j = KSEL - 1; j > 0; --j)
                    if (d1[j] < d1[j - 1]) {
                        float td = d1[j]; d1[j] = d1[j - 1]; d1[j - 1] = td;
                        int   ti = i1[j]; i1[j] = i1[j - 1]; i1[j - 1] = ti;
                    }
            }
        }
    }

    // Wave-level exact merge: 64 sorted 16-lists -> slice top-16 per test point (R1 verbatim)
#pragma unroll
    for (int j = 0; j < 2; ++j) {
        float hd = j ? d1[0] : d0[0];
        int   hi = j ? i1[0] : i0[0];
        int c = 0;
        float od = 0.0f; int oi = 0;
        for (int r = 0; r < KSEL; ++r) {
            float wd = hd; int wi = hi;
#pragma unroll
            for (int sh = 1; sh < 64; sh <<= 1) {
                const float xd = __shfl_xor(wd, sh);
                const int   xi = __shfl_xor(wi, sh);
                if (xd < wd || (xd == wd && xi < wi)) { wd = xd; wi = xi; }
            }
            if (wi == hi) {            // this lane supplied the winner (idx unique)
                ++c;
                float nd = FLT_MAX; int ni = INT_MAX;
#pragma unroll
                for (int q = 1; q < KSEL; ++q)
                    if (c == q) { nd = j ? d1[q] : d0[q]; ni = j ? i1[q] : i0[q]; }
                hd = nd; hi = ni;
            }
            if (lane == r) { od = wd; oi = wi; }
        }
        const int tp = g * TB + 2 * w + j;
        if (lane < KSEL) {
            cand_d[((size_t)tp * nslices + s) * KSEL + lane] = od;
            cand_i[((size_t)tp * nslices + s) * KSEL + lane] = oi;
        }
    }
}

__global__ __launch_bounds__(64) void knn_final(
    const float* __restrict__ cand_d, const int* __restrict__ cand_i,
    const float* __restrict__ ttarget, int* __restrict__ out, int nslices)
{
    const int b     = blockIdx.x;
    const int lane  = threadIdx.x;
    const int ncand = nslices * KSEL;

    float ld[KSEL]; int li[KSEL];
#pragma unroll
    for (int j = 0; j < KSEL; ++j) { ld[j] = FLT_MAX; li[j] = INT_MAX; }

    for (int q = lane; q < ncand; q += 64) {
        const float dv = cand_d[(size_t)b * ncand + q];
        const int   iv = cand_i[(size_t)b * ncand + q];
        if (dv < ld[KSEL - 1] || (dv == ld[KSEL - 1] && iv < li[KSEL - 1])) {
            ld[KSEL - 1] = dv; li[KSEL - 1] = iv;
#pragma unroll
            for (int j = KSEL - 1; j > 0; --j)
                if (ld[j] < ld[j - 1] || (ld[j] == ld[j - 1] && li[j] < li[j - 1])) {
                    float td = ld[j]; ld[j] = ld[j - 1]; ld[j - 1] = td;
                    int   ti = li[j]; li[j] = li[j - 1]; li[j - 1] = ti;
                }
        }
    }

    float hd = ld[0]; int hi = li[0]; int c = 0;
    float v = 0.0f;
    for (int r = 0; r < KSEL; ++r) {
        float wd = hd; int wi = hi;
#pragma unroll
        for (int sh = 1; sh < 64; sh <<= 1) {
            const float xd = __shfl_xor(wd, sh);
            const int   xi = __shfl_xor(wi, sh);
            if (xd < wd || (xd == wd && xi < wi)) { wd = xd; wi = xi; }
        }
        if (wi == hi) {
            ++c;
            float nd = FLT_MAX; int ni = INT_MAX;
#pragma unroll
            for (int q = 1; q < KSEL; ++q)
                if (c == q) { nd = ld[q]; ni = li[q]; }
            hd = nd; hi = ni;
        }
        if (lane < NCLS) v += ttarget[(size_t)wi * NCLS + lane];  // one-hot vote
    }

    float bv = (lane < NCLS) ? v : -1.0f;
    int   bc = lane;
#pragma unroll
    for (int sh = 1; sh < 64; sh <<= 1) {
        const float xv = __shfl_xor(bv, sh);
        const int   xc = __shfl_xor(bc, sh);
        if (xv > bv || (xv == bv && xc < bc)) { bv = xv; bc = xc; }  // tie -> lowest class
    }
    if (lane == 0) out[b] = bc;
}

extern "C" void kernel_launch(void* const* d_in, const int* in_sizes, int n_in,
                              void* d_out, int out_size, void* d_ws, size_t ws_size,
                              hipStream_t stream) {
    const float* train   = (const float*)d_in[0];
    const float* ttarget = (const float*)d_in[1];
    const float* xtest   = (const float*)d_in[2];
    int* out = (int*)d_out;

    int nslices = 32;
    while (nslices > 1 && (size_t)BQ * nslices * KSEL * 8 > ws_size) nslices >>= 1;
    const int slice_len = (NTRAIN + nslices - 1) / nslices;

    float* cand_d = (float*)d_ws;
    int*   cand_i = (int*)((char*)d_ws + (size_t)BQ * nslices * KSEL * sizeof(float));

    hipLaunchKernelGGL(knn_partial, dim3(GROUPS * nslices), dim3(THREADS), 0, stream,
                       train, xtest, cand_d, cand_i, nslices, slice_len);
    hipLaunchKernelGGL(knn_final, dim3(BQ), dim3(64), 0, stream,
                       cand_d, cand_i, ttarget, out, nslices);
}

// Round 4
// 279.801 us; speedup vs baseline: 1.2472x; 1.0128x over previous
//
#include <hip/hip_runtime.h>
#include <cfloat>
#include <climits>

#define NTRAIN 50000
#define DIM 64
#define BQ 128
#define NCLS 10
#define KSEL 16
#define WPB 8                       // waves per block in knn_scan
#define SCAN_THREADS (WPB * 64)

// Query-per-lane, broadcast-row scan.
// Lane l of every wave owns query (half*64 + l) in 64 VGPRs.
// Rows are wave-uniform (scalar-loadable): per row*query only 4 B of load
// traffic amortized -> purely VALU-bound.
__global__ __launch_bounds__(SCAN_THREADS, 2) void knn_scan(
    const float* __restrict__ train, const float* __restrict__ xtest,
    float* __restrict__ cand_d, int* __restrict__ cand_i,
    int stripes, int stripe_len)
{
    __shared__ float sdl[WPB][64][KSEL];   // 32 KB
    __shared__ int   sil[WPB][64][KSEL];   // 32 KB

    const int bx     = blockIdx.x;
    const int half   = bx & 1;
    const int stripe = bx >> 1;
    const int tid    = threadIdx.x;
    const int lane   = tid & 63;
    const int w      = __builtin_amdgcn_readfirstlane(tid >> 6); // wave-uniform

    const int r0 = stripe * stripe_len;
    const int r1 = min(NTRAIN, r0 + stripe_len);

    // per-lane query -> registers (lane-distinct, 64 VGPR)
    const int q = half * 64 + lane;
    float qreg[DIM];
    {
        const float* qp = xtest + (size_t)q * DIM;
#pragma unroll
        for (int c = 0; c < DIM / 4; ++c) {
            const float4 v = *(const float4*)(qp + 4 * c);
            qreg[4 * c + 0] = v.x; qreg[4 * c + 1] = v.y;
            qreg[4 * c + 2] = v.z; qreg[4 * c + 3] = v.w;
        }
    }

    // per-lane top-16, ascending; strict '<' keeps lowest index on ties
    // (rows visited in increasing order within a wave)
    float dk[KSEL]; int ik[KSEL];
#pragma unroll
    for (int j = 0; j < KSEL; ++j) { dk[j] = FLT_MAX; ik[j] = INT_MAX; }

    for (int r = r0 + w; r < r1; r += WPB) {
        const float* rp = train + (size_t)r * DIM;   // uniform address -> s_load
        float a[4] = {0.f, 0.f, 0.f, 0.f};
#pragma unroll
        for (int c = 0; c < DIM / 4; ++c) {
            const float4 t = *(const float4*)(rp + 4 * c);
            const float s = fabsf(t.x - qreg[4 * c + 0]) + fabsf(t.y - qreg[4 * c + 1]) +
                            fabsf(t.z - qreg[4 * c + 2]) + fabsf(t.w - qreg[4 * c + 3]);
            a[c & 3] += s;           // static after full unroll
        }
        const float d = (a[0] + a[1]) + (a[2] + a[3]);
        if (d < dk[KSEL - 1]) {
            dk[KSEL - 1] = d; ik[KSEL - 1] = r;
#pragma unroll
            for (int j = KSEL - 1; j > 0; --j)
                if (dk[j] < dk[j - 1]) {
                    float td = dk[j]; dk[j] = dk[j - 1]; dk[j - 1] = td;
                    int   ti = ik[j]; ik[j] = ik[j - 1]; ik[j - 1] = ti;
                }
        }
    }

    // block merge: 8 waves' lists (disjoint rows, same 64 queries) -> top-16
#pragma unroll
    for (int j = 0; j < KSEL; ++j) { sdl[w][lane][j] = dk[j]; sil[w][lane][j] = ik[j]; }
    __syncthreads();

    if (w == 0) {
        float md[KSEL]; int mi[KSEL];
#pragma unroll
        for (int j = 0; j < KSEL; ++j) { md[j] = FLT_MAX; mi[j] = INT_MAX; }
        for (int v = 0; v < WPB; ++v)
            for (int j = 0; j < KSEL; ++j) {
                const float f  = sdl[v][lane][j];
                const int   fi = sil[v][lane][j];
                if (f < md[KSEL - 1] || (f == md[KSEL - 1] && fi < mi[KSEL - 1])) {
                    md[KSEL - 1] = f; mi[KSEL - 1] = fi;
#pragma unroll
                    for (int t = KSEL - 1; t > 0; --t)
                        if (md[t] < md[t - 1] || (md[t] == md[t - 1] && mi[t] < mi[t - 1])) {
                            float td = md[t]; md[t] = md[t - 1]; md[t - 1] = td;
                            int   ti = mi[t]; mi[t] = mi[t - 1]; mi[t - 1] = ti;
                        }
                }
            }
        const int ncand = stripes * KSEL;
#pragma unroll
        for (int j = 0; j < KSEL; ++j) {
            cand_d[(size_t)q * ncand + stripe * KSEL + j] = md[j];
            cand_i[(size_t)q * ncand + stripe * KSEL + j] = mi[j];
        }
    }
}

// exact lex-(d,idx) top-16 over candidates, vote, argmax (R1-proven epilogue)
__global__ __launch_bounds__(64) void knn_final(
    const float* __restrict__ cand_d, const int* __restrict__ cand_i,
    const float* __restrict__ ttarget, int* __restrict__ out, int ncand)
{
    const int b    = blockIdx.x;
    const int lane = threadIdx.x;

    float ld[KSEL]; int li[KSEL];
#pragma unroll
    for (int j = 0; j < KSEL; ++j) { ld[j] = FLT_MAX; li[j] = INT_MAX; }

    for (int c = lane; c < ncand; c += 64) {
        const float dv = cand_d[(size_t)b * ncand + c];
        const int   iv = cand_i[(size_t)b * ncand + c];
        if (dv < ld[KSEL - 1] || (dv == ld[KSEL - 1] && iv < li[KSEL - 1])) {
            ld[KSEL - 1] = dv; li[KSEL - 1] = iv;
#pragma unroll
            for (int j = KSEL - 1; j > 0; --j)
                if (ld[j] < ld[j - 1] || (ld[j] == ld[j - 1] && li[j] < li[j - 1])) {
                    float td = ld[j]; ld[j] = ld[j - 1]; ld[j - 1] = td;
                    int   ti = li[j]; li[j] = li[j - 1]; li[j - 1] = ti;
                }
        }
    }

    float hd = ld[0]; int hi = li[0]; int c = 0;
    float v = 0.0f;
    for (int r = 0; r < KSEL; ++r) {
        float wd = hd; int wi = hi;
#pragma unroll
        for (int sh = 1; sh < 64; sh <<= 1) {
            const float xd = __shfl_xor(wd, sh);
            const int   xi = __shfl_xor(wi, sh);
            if (xd < wd || (xd == wd && xi < wi)) { wd = xd; wi = xi; }
        }
        if (wi == hi) {
            ++c;
            float nd = FLT_MAX; int ni = INT_MAX;
#pragma unroll
            for (int t = 1; t < KSEL; ++t)
                if (c == t) { nd = ld[t]; ni = li[t]; }
            hd = nd; hi = ni;
        }
        if (lane < NCLS) v += ttarget[(size_t)wi * NCLS + lane];  // one-hot vote
    }

    float bv = (lane < NCLS) ? v : -1.0f;
    int   bc = lane;
#pragma unroll
    for (int sh = 1; sh < 64; sh <<= 1) {
        const float xv = __shfl_xor(bv, sh);
        const int   xc = __shfl_xor(bc, sh);
        if (xv > bv || (xv == bv && xc < bc)) { bv = xv; bc = xc; }  // tie -> lowest class
    }
    if (lane == 0) out[b] = bc;
}

extern "C" void kernel_launch(void* const* d_in, const int* in_sizes, int n_in,
                              void* d_out, int out_size, void* d_ws, size_t ws_size,
                              hipStream_t stream) {
    const float* train   = (const float*)d_in[0];
    const float* ttarget = (const float*)d_in[1];
    const float* xtest   = (const float*)d_in[2];
    int* out = (int*)d_out;

    // candidate storage: BQ * stripes * 16 * 8 B; degrade stripes if ws small
    int stripes = 128;
    while (stripes > 16 && (size_t)BQ * stripes * KSEL * 8 > ws_size) stripes >>= 1;
    const int stripe_len = (NTRAIN + stripes - 1) / stripes;
    const int ncand = stripes * KSEL;

    float* cand_d = (float*)d_ws;
    int*   cand_i = (int*)((char*)d_ws + (size_t)BQ * ncand * sizeof(float));

    hipLaunchKernelGGL(knn_scan, dim3(2 * stripes), dim3(SCAN_THREADS), 0, stream,
                       train, xtest, cand_d, cand_i, stripes, stripe_len);
    hipLaunchKernelGGL(knn_final, dim3(BQ), dim3(64), 0, stream,
                       cand_d, cand_i, ttarget, out, ncand);
}

// Round 6
// 142.916 us; speedup vs baseline: 2.4418x; 1.9578x over previous
//
#include <hip/hip_runtime.h>
#include <cfloat>
#include <climits>
#include <stdint.h>

#define NTRAIN 50000
#define DIM 64
#define BQ 128
#define NCLS 10
#define KSEL 16
#define QPB 32                 // queries per block
#define QG (BQ / QPB)          // 4 query groups
#define THREADS 256            // 4 waves
#define TROWS 256              // rows staged per tile (64 per wave)
#define TPAD 68                // float4 rows; bank 4*(row%8) -> 8 disjoint groups (R1/R2: 0 conflicts)

// packed candidate: (f32 distance bits << 32) | row  -> u64 '<' == lex (d, idx)
__device__ __forceinline__ uint64_t pack_di(float d, int r) {
    return ((uint64_t)__float_as_uint(d) << 32) | (uint32_t)r;
}

// sorted-ascending top-16 insert; 16-element arrays promote to VGPRs (R1-proven size)
__device__ __forceinline__ void ins16(uint64_t (&K)[KSEL], uint64_t pk) {
    if (pk < K[KSEL - 1]) {
        K[KSEL - 1] = pk;
#pragma unroll
        for (int j = KSEL - 1; j > 0; --j)
            if (K[j] < K[j - 1]) { uint64_t t = K[j]; K[j] = K[j - 1]; K[j - 1] = t; }
    }
}

__device__ __forceinline__ uint64_t adv16(const uint64_t (&K)[KSEL], int c) {
    uint64_t nh = ~0ULL;
#pragma unroll
    for (int q = 1; q < KSEL; ++q)
        if (c == q) nh = K[q];
    return nh;
}

// merge 8 sorted lists held by the 8 rg-lanes of each qg-group.
// Group = CONSECUTIVE lanes 8*qg..8*qg+7 (rg = bits 0-2) -> butterfly xor 1/2/4.
// (R5 bug: used 8/16/32, which merges across qg -> mixed queries' lists.)
// Winner of round r written to dst[r] by the lane with rg == r&7.
__device__ __forceinline__ void wave_merge8(const uint64_t (&K)[KSEL], int rg, uint64_t* dst) {
    uint64_t h = K[0]; int c = 0;
#pragma unroll
    for (int r = 0; r < KSEL; ++r) {
        uint64_t m = h, o;
        o = __shfl_xor((unsigned long long)m, 1); if (o < m) m = o;
        o = __shfl_xor((unsigned long long)m, 2); if (o < m) m = o;
        o = __shfl_xor((unsigned long long)m, 4); if (o < m) m = o;
        if (m == h) { ++c; h = adv16(K, c); }
        if (rg == (r & 7)) dst[r] = m;
    }
}

__global__ __launch_bounds__(THREADS, 1) void knn_scan(
    const float* __restrict__ train, const float* __restrict__ xtest,
    uint64_t* __restrict__ cand, int S, int stripe_len)
{
    __shared__ float qs[QPB * TPAD];                        // 8.7 KB
    __shared__ __align__(16) float ts[TROWS * TPAD];        // 69.6 KB (aliased by merge)

    const int bx     = blockIdx.x;
    const int stripe = bx % S;
    const int qgrp   = bx / S;
    const int q0     = qgrp * QPB;
    const int tid    = threadIdx.x;
    const int w      = tid >> 6;
    const int lane   = tid & 63;
    const int qg     = lane >> 3;      // 0..7 : query sub-index (group = consecutive 8 lanes)
    const int rg     = lane & 7;       // 0..7 : row sub-index (within group)

    const int r0 = stripe * stripe_len;
    const int r1 = min(NTRAIN, r0 + stripe_len);

    // stage the block's 32 queries once
    for (int f = tid; f < QPB * (DIM / 4); f += THREADS) {
        const int ql = f >> 4, c = f & 15;
        *(float4*)&qs[ql * TPAD + 4 * c] =
            *(const float4*)&xtest[(size_t)(q0 + ql) * DIM + 4 * c];
    }

    // per-lane top-16 for 4 queries (qg + 8i), packed u64
    uint64_t k0[KSEL], k1[KSEL], k2[KSEL], k3[KSEL];
#pragma unroll
    for (int j = 0; j < KSEL; ++j) { k0[j] = ~0ULL; k1[j] = ~0ULL; k2[j] = ~0ULL; k3[j] = ~0ULL; }

    for (int base = r0; base < r1; base += TROWS) {
        const int nr = min(TROWS, r1 - base);
        __syncthreads();                         // previous tile's readers done
        for (int f = tid; f < nr * (DIM / 4); f += THREADS) {
            const int r = f >> 4, c = f & 15;
            *(float4*)&ts[r * TPAD + 4 * c] =
                *(const float4*)&train[(size_t)(base + r) * DIM + 4 * c];
        }
        __syncthreads();                         // tile ready

        // wave tile: 32q x 64r; lane tile: 4q (qg+8i) x 8r (w*64+rg+8j)
        float acc[4][8];
#pragma unroll
        for (int i = 0; i < 4; ++i)
#pragma unroll
            for (int j = 0; j < 8; ++j) acc[i][j] = 0.0f;

#pragma unroll 4
        for (int c = 0; c < DIM / 4; ++c) {
            float4 qv[4], tv[8];
#pragma unroll
            for (int i = 0; i < 4; ++i)
                qv[i] = *(const float4*)&qs[(qg + 8 * i) * TPAD + 4 * c];
#pragma unroll
            for (int j = 0; j < 8; ++j)
                tv[j] = *(const float4*)&ts[(w * 64 + rg + 8 * j) * TPAD + 4 * c];
#pragma unroll
            for (int i = 0; i < 4; ++i)
#pragma unroll
                for (int j = 0; j < 8; ++j) {
                    const float s01 = fabsf(tv[j].x - qv[i].x) + fabsf(tv[j].y - qv[i].y);
                    const float s23 = fabsf(tv[j].z - qv[i].z) + fabsf(tv[j].w - qv[i].w);
                    acc[i][j] += s01 + s23;
                }
        }

        const int rb = base + w * 64 + rg;
#pragma unroll
        for (int j = 0; j < 8; ++j) {
            const int r = rb + 8 * j;
            if (r < r1) {                        // tail rows (stale LDS) rejected here
                ins16(k0, pack_di(acc[0][j], r));
                ins16(k1, pack_di(acc[1][j], r));
                ins16(k2, pack_di(acc[2][j], r));
                ins16(k3, pack_di(acc[3][j], r));
            }
        }
    }

    // ---- block-level merge: 32 lists/query -> 16/query ----
    __syncthreads();                             // ts free for reuse
    uint64_t* mg = (uint64_t*)ts;                // [4 waves][QPB][17] (pad 17 -> conflict-free)
    wave_merge8(k0, rg, &mg[((size_t)w * QPB + qg +  0) * 17]);
    wave_merge8(k1, rg, &mg[((size_t)w * QPB + qg +  8) * 17]);
    wave_merge8(k2, rg, &mg[((size_t)w * QPB + qg + 16) * 17]);
    wave_merge8(k3, rg, &mg[((size_t)w * QPB + qg + 24) * 17]);
    __syncthreads();

    if (tid < QPB) {                             // thread t owns query q0+t
        uint64_t kk[KSEL];
#pragma unroll
        for (int j = 0; j < KSEL; ++j) kk[j] = ~0ULL;
        for (int v = 0; v < 4; ++v)
#pragma unroll
            for (int j = 0; j < KSEL; ++j)
                ins16(kk, mg[((size_t)v * QPB + tid) * 17 + j]);
#pragma unroll
        for (int j = 0; j < KSEL; ++j)
            cand[((size_t)(q0 + tid) * S + stripe) * KSEL + j] = kk[j];
    }
}

// per-query: exact top-16 over S*16 candidates, one-hot vote, argmax
__global__ __launch_bounds__(64) void knn_final(
    const uint64_t* __restrict__ cand, const float* __restrict__ ttarget,
    int* __restrict__ out, int ncand)
{
    const int b = blockIdx.x, lane = threadIdx.x;

    uint64_t k[KSEL];
#pragma unroll
    for (int j = 0; j < KSEL; ++j) k[j] = ~0ULL;
    for (int c = lane; c < ncand; c += 64)
        ins16(k, cand[(size_t)b * ncand + c]);

    // 64-list wave merge (R1-proven cursor pattern, u64), vote on the fly
    uint64_t h = k[0]; int c = 0;
    float v = 0.0f;
#pragma unroll
    for (int r = 0; r < KSEL; ++r) {
        uint64_t m = h, o;
#pragma unroll
        for (int sh = 1; sh < 64; sh <<= 1) {
            o = __shfl_xor((unsigned long long)m, sh);
            if (o < m) m = o;
        }
        if (m == h) { ++c; h = adv16(k, c); }
        const int wi = (int)(uint32_t)(m & 0xFFFFFFFFu);
        if (lane < NCLS) v += ttarget[(size_t)wi * NCLS + lane];  // one-hot vote
    }

    float bv = (lane < NCLS) ? v : -1.0f;
    int   bc = lane;
#pragma unroll
    for (int sh = 1; sh < 64; sh <<= 1) {
        const float xv = __shfl_xor(bv, sh);
        const int   xc = __shfl_xor(bc, sh);
        if (xv > bv || (xv == bv && xc < bc)) { bv = xv; bc = xc; }  // tie -> lowest class
    }
    if (lane == 0) out[b] = bc;
}

extern "C" void kernel_launch(void* const* d_in, const int* in_sizes, int n_in,
                              void* d_out, int out_size, void* d_ws, size_t ws_size,
                              hipStream_t stream) {
    const float* train   = (const float*)d_in[0];
    const float* ttarget = (const float*)d_in[1];
    const float* xtest   = (const float*)d_in[2];
    int* out = (int*)d_out;

    int S = 64;                                  // cand = 128*S*16*8 B  (S=64 -> 1 MB)
    while (S > 8 && (size_t)BQ * S * KSEL * 8 > ws_size) S >>= 1;
    const int stripe_len = (NTRAIN + S - 1) / S;

    uint64_t* cand = (uint64_t*)d_ws;

    hipLaunchKernelGGL(knn_scan, dim3(QG * S), dim3(THREADS), 0, stream,
                       train, xtest, cand, S, stripe_len);
    hipLaunchKernelGGL(knn_final, dim3(BQ), dim3(64), 0, stream,
                       cand, ttarget, out, S * KSEL);
}

// Round 7
// 138.758 us; speedup vs baseline: 2.5150x; 1.0300x over previous
//
#include <hip/hip_runtime.h>
#include <cfloat>
#include <climits>
#include <stdint.h>

#define NTRAIN 50000
#define DIM 64
#define BQ 128
#define NCLS 10
#define KSEL 16
#define QPB 32                 // queries per block (scan)
#define QG (BQ / QPB)          // 4 query groups
#define THREADS 512            // 8 waves
#define TROWS 512              // rows staged per tile (64 per wave)
#define TPAD 68                // float4 rows; 8-lane phases conflict-free (R1/R2/R6: 0 conflicts)
#define NSAMP 1024             // sample rows for tau
#define SSTRIPES 64            // cand stripes: 128*64*16*8 = 1 MB (ws-safe, R2 evidence >=1.45 MB)
#define MARGIN 1e-2f

// packed candidate: (f32 distance bits << 32) | row  -> u64 '<' == lex (d, idx)
__device__ __forceinline__ uint64_t pack_di(float d, int r) {
    return ((uint64_t)__float_as_uint(d) << 32) | (uint32_t)r;
}

// sorted-ascending top-16 insert (exact for any pass count); 16-elem arrays promote
__device__ __forceinline__ void ins16(uint64_t (&K)[KSEL], uint64_t pk) {
    if (pk < K[KSEL - 1]) {
        K[KSEL - 1] = pk;
#pragma unroll
        for (int j = KSEL - 1; j > 0; --j)
            if (K[j] < K[j - 1]) { uint64_t t = K[j]; K[j] = K[j - 1]; K[j - 1] = t; }
    }
}

__device__ __forceinline__ uint64_t adv16(const uint64_t (&K)[KSEL], int c) {
    uint64_t nh = ~0ULL;
#pragma unroll
    for (int q = 1; q < KSEL; ++q)
        if (c == q) nh = K[q];
    return nh;
}

// merge 8 sorted lists held by consecutive lanes 8*qg..8*qg+7 (rg = bits 0-2)
// -> butterfly xor 1/2/4 (R5 bug fixed in R6). Winner r -> dst[r] by lane rg==r&7.
__device__ __forceinline__ void wave_merge8(const uint64_t (&K)[KSEL], int rg, uint64_t* dst) {
    uint64_t h = K[0]; int c = 0;
#pragma unroll
    for (int r = 0; r < KSEL; ++r) {
        uint64_t m = h, o;
        o = __shfl_xor((unsigned long long)m, 1); if (o < m) m = o;
        o = __shfl_xor((unsigned long long)m, 2); if (o < m) m = o;
        o = __shfl_xor((unsigned long long)m, 4); if (o < m) m = o;
        if (m == h) { ++c; h = adv16(K, c); }
        if (rg == (r & 7)) dst[r] = m;
    }
}

// K1: tau[q] = (16th smallest distance over rows 0..NSAMP-1) + MARGIN.
// Distance arithmetic is a bit-exact replica of knn_scan's chain:
//   acc += (|dx|+|dy|) + (|dz|+|dw|), left-assoc over c (IEEE, no fast-math).
__global__ __launch_bounds__(64) void knn_tau(
    const float* __restrict__ train, const float* __restrict__ xtest,
    float* __restrict__ tau)
{
    const int q = blockIdx.x, lane = threadIdx.x;

    float4 qv[DIM / 4];
    {
        const float* qp = xtest + (size_t)q * DIM;
#pragma unroll
        for (int c = 0; c < DIM / 4; ++c) qv[c] = *(const float4*)(qp + 4 * c);
    }

    uint64_t K[KSEL];
#pragma unroll
    for (int j = 0; j < KSEL; ++j) K[j] = ~0ULL;

    for (int t = 0; t < NSAMP / 64; ++t) {
        const int r = lane + 64 * t;
        const float* rp = train + (size_t)r * DIM;
        float acc = 0.0f;
#pragma unroll
        for (int c = 0; c < DIM / 4; ++c) {
            const float4 tv = *(const float4*)(rp + 4 * c);
            const float s01 = fabsf(tv.x - qv[c].x) + fabsf(tv.y - qv[c].y);
            const float s23 = fabsf(tv.z - qv[c].z) + fabsf(tv.w - qv[c].w);
            acc += s01 + s23;
        }
        ins16(K, pack_di(acc, r));
    }

    // full-wave 64-list cursor merge (R1-proven); last winner = 16th smallest
    uint64_t h = K[0]; int c = 0; uint64_t last = ~0ULL;
#pragma unroll
    for (int r = 0; r < KSEL; ++r) {
        uint64_t m = h, o;
#pragma unroll
        for (int sh = 1; sh < 64; sh <<= 1) {
            o = __shfl_xor((unsigned long long)m, sh);
            if (o < m) m = o;
        }
        if (m == h) { ++c; h = adv16(K, c); }
        last = m;
    }
    if (lane == 0) tau[q] = __uint_as_float((uint32_t)(last >> 32)) + MARGIN;
}

// K2: full scan; distance hot loop + cold gated exact top-16 (pass rate ~7e-4)
__global__ __launch_bounds__(THREADS, 2) void knn_scan(
    const float* __restrict__ train, const float* __restrict__ xtest,
    const float* __restrict__ tau, uint64_t* __restrict__ cand, int stripe_len)
{
    __shared__ float qs[QPB * TPAD];                        // 8.7 KB
    __shared__ __align__(16) float ts[TROWS * TPAD];        // 139.3 KB (aliased by merge)

    const int bx     = blockIdx.x;
    const int stripe = bx % SSTRIPES;
    const int qgrp   = bx / SSTRIPES;
    const int q0     = qgrp * QPB;
    const int tid    = threadIdx.x;
    const int w      = tid >> 6;
    const int lane   = tid & 63;
    const int qg     = lane >> 3;      // 0..7 query sub-index (consecutive-8 groups)
    const int rg     = lane & 7;       // 0..7 row sub-index

    const int r0 = stripe * stripe_len;
    const int r1 = min(NTRAIN, r0 + stripe_len);

    for (int f = tid; f < QPB * (DIM / 4); f += THREADS) {
        const int ql = f >> 4, c = f & 15;
        *(float4*)&qs[ql * TPAD + 4 * c] =
            *(const float4*)&xtest[(size_t)(q0 + ql) * DIM + 4 * c];
    }

    float tauv[4];
#pragma unroll
    for (int i = 0; i < 4; ++i) tauv[i] = tau[q0 + qg + 8 * i];

    uint64_t k0[KSEL], k1[KSEL], k2[KSEL], k3[KSEL];
#pragma unroll
    for (int j = 0; j < KSEL; ++j) { k0[j] = ~0ULL; k1[j] = ~0ULL; k2[j] = ~0ULL; k3[j] = ~0ULL; }

    for (int base = r0; base < r1; base += TROWS) {
        const int nr = min(TROWS, r1 - base);
        __syncthreads();                         // previous tile's readers done
        for (int f = tid; f < nr * (DIM / 4); f += THREADS) {
            const int r = f >> 4, c = f & 15;
            *(float4*)&ts[r * TPAD + 4 * c] =
                *(const float4*)&train[(size_t)(base + r) * DIM + 4 * c];
        }
        __syncthreads();                         // tile ready

        // wave tile: 32q x 64r; lane tile: 4q (qg+8i) x 8r (w*64+rg+8j)
        float acc[4][8];
#pragma unroll
        for (int i = 0; i < 4; ++i)
#pragma unroll
            for (int j = 0; j < 8; ++j) acc[i][j] = 0.0f;

#pragma unroll 4
        for (int c = 0; c < DIM / 4; ++c) {
            float4 qv[4], tv[8];
#pragma unroll
            for (int i = 0; i < 4; ++i)
                qv[i] = *(const float4*)&qs[(qg + 8 * i) * TPAD + 4 * c];
#pragma unroll
            for (int j = 0; j < 8; ++j)
                tv[j] = *(const float4*)&ts[(w * 64 + rg + 8 * j) * TPAD + 4 * c];
#pragma unroll
            for (int i = 0; i < 4; ++i)
#pragma unroll
                for (int j = 0; j < 8; ++j) {
                    const float s01 = fabsf(tv[j].x - qv[i].x) + fabsf(tv[j].y - qv[i].y);
                    const float s23 = fabsf(tv[j].z - qv[i].z) + fabsf(tv[j].w - qv[i].w);
                    acc[i][j] += s01 + s23;
                }
        }

        // gated inserts: true top-16 all satisfy d <= tau (tau >= global 16th)
        const int rb = base + w * 64 + rg;
#pragma unroll
        for (int j = 0; j < 8; ++j) {
            const int r = rb + 8 * j;
            if (r < r1) {
                if (acc[0][j] <= tauv[0]) ins16(k0, pack_di(acc[0][j], r));
                if (acc[1][j] <= tauv[1]) ins16(k1, pack_di(acc[1][j], r));
                if (acc[2][j] <= tauv[2]) ins16(k2, pack_di(acc[2][j], r));
                if (acc[3][j] <= tauv[3]) ins16(k3, pack_di(acc[3][j], r));
            }
        }
    }

    // block merge: 64 lists/query (8 waves x 8 rg) -> 16/query
    __syncthreads();                             // ts free for reuse
    uint64_t* mg = (uint64_t*)ts;                // [8 waves][QPB][17] = 34.8 KB
    wave_merge8(k0, rg, &mg[((size_t)w * QPB + qg +  0) * 17]);
    wave_merge8(k1, rg, &mg[((size_t)w * QPB + qg +  8) * 17]);
    wave_merge8(k2, rg, &mg[((size_t)w * QPB + qg + 16) * 17]);
    wave_merge8(k3, rg, &mg[((size_t)w * QPB + qg + 24) * 17]);
    __syncthreads();

    if (tid < QPB) {                             // thread t owns query q0+t
        uint64_t kk[KSEL];
#pragma unroll
        for (int j = 0; j < KSEL; ++j) kk[j] = ~0ULL;
        for (int v = 0; v < 8; ++v)
#pragma unroll
            for (int j = 0; j < KSEL; ++j)
                ins16(kk, mg[((size_t)v * QPB + tid) * 17 + j]);   // sentinels skip cheaply
#pragma unroll
        for (int j = 0; j < KSEL; ++j)
            cand[((size_t)(q0 + tid) * SSTRIPES + stripe) * KSEL + j] = kk[j];
    }
}

// K3: exact top-16 over 64*16 candidates, one-hot vote, argmax
__global__ __launch_bounds__(64) void knn_final(
    const uint64_t* __restrict__ cand, const float* __restrict__ ttarget,
    int* __restrict__ out, int ncand)
{
    const int b = blockIdx.x, lane = threadIdx.x;

    uint64_t k[KSEL];
#pragma unroll
    for (int j = 0; j < KSEL; ++j) k[j] = ~0ULL;
    for (int c = lane; c < ncand; c += 64)
        ins16(k, cand[(size_t)b * ncand + c]);

    uint64_t h = k[0]; int c = 0;
    float v = 0.0f;
#pragma unroll
    for (int r = 0; r < KSEL; ++r) {
        uint64_t m = h, o;
#pragma unroll
        for (int sh = 1; sh < 64; sh <<= 1) {
            o = __shfl_xor((unsigned long long)m, sh);
            if (o < m) m = o;
        }
        if (m == h) { ++c; h = adv16(k, c); }
        const int wi = (int)(uint32_t)(m & 0xFFFFFFFFu);   // winners are always real rows
        if (lane < NCLS) v += ttarget[(size_t)wi * NCLS + lane];
    }

    float bv = (lane < NCLS) ? v : -1.0f;
    int   bc = lane;
#pragma unroll
    for (int sh = 1; sh < 64; sh <<= 1) {
        const float xv = __shfl_xor(bv, sh);
        const int   xc = __shfl_xor(bc, sh);
        if (xv > bv || (xv == bv && xc < bc)) { bv = xv; bc = xc; }  // tie -> lowest class
    }
    if (lane == 0) out[b] = bc;
}

extern "C" void kernel_launch(void* const* d_in, const int* in_sizes, int n_in,
                              void* d_out, int out_size, void* d_ws, size_t ws_size,
                              hipStream_t stream) {
    const float* train   = (const float*)d_in[0];
    const float* ttarget = (const float*)d_in[1];
    const float* xtest   = (const float*)d_in[2];
    int* out = (int*)d_out;

    const int stripe_len = (NTRAIN + SSTRIPES - 1) / SSTRIPES;   // 782

    float*    tau  = (float*)d_ws;                                // 512 B
    uint64_t* cand = (uint64_t*)((char*)d_ws + 512);              // 1 MB

    hipLaunchKernelGGL(knn_tau, dim3(BQ), dim3(64), 0, stream, train, xtest, tau);
    hipLaunchKernelGGL(knn_scan, dim3(QG * SSTRIPES), dim3(THREADS), 0, stream,
                       train, xtest, tau, cand, stripe_len);
    hipLaunchKernelGGL(knn_final, dim3(BQ), dim3(64), 0, stream,
                       cand, ttarget, out, SSTRIPES * KSEL);
}